// Round 3
// baseline (540.681 us; speedup 1.0000x reference)
//
#include <hip/hip_runtime.h>
#include <cstdint>

#define NN 50000
#define NE 640000
#define NG 128
#define HD 128
#define FN 64
#define FE 16
#define FL 200
#define FPOC 100
#define NSTACK 3
#define NBUK 196  // ceil(NN/256): dst-buckets of 256 nodes; bucket = d>>8

typedef unsigned short ushort_t;
typedef short short8 __attribute__((ext_vector_type(8)));
typedef float f32x4 __attribute__((ext_vector_type(4)));

__device__ __forceinline__ ushort_t f2bf(float f) {
    unsigned u = __float_as_uint(f);
    unsigned r = (u + 0x7fffu + ((u >> 16) & 1u)) >> 16;
    return (ushort_t)r;
}
__device__ __forceinline__ float bf2f(ushort_t u) {
    return __uint_as_float(((unsigned)u) << 16);
}

// ---------------- CSR build (round-12 bucketed scatter, round-13 output split) ----
// Round-1 rocprof: direct int2 scatter = 48us, 42.5MB writes for a 5.1MB csr
// (cross-XCD line re-dirtying). Round-12 two-level bucketed scatter fixed it
// (dur 397->357). Round-13: csr split into csrc (src | dlocal16<<20) and
// cedge (edge id) so gather kernels stream 4B/edge instead of 8B.

__global__ void hist_kernel(const int* __restrict__ ei, int* __restrict__ bucket_cnt) {
    __shared__ int l[NBUK];
    int t = threadIdx.x;
    if (t < NBUK) l[t] = 0;
    __syncthreads();
    int base = blockIdx.x * 2048;
#pragma unroll
    for (int i = 0; i < 8; ++i) {
        int e = base + i * 256 + t;
        if (e < NE) atomicAdd(&l[ei[NE + e] >> 8], 1);
    }
    __syncthreads();
    if (t < NBUK && l[t]) atomicAdd(&bucket_cnt[t], l[t]);
}

__global__ void scan_kernel(const int* __restrict__ bucket_cnt,
                            int* __restrict__ bucket_base, int* __restrict__ bucket_cur) {
    __shared__ int s[256];
    int t = threadIdx.x;
    int v = (t < NBUK) ? bucket_cnt[t] : 0;
    s[t] = v;
    __syncthreads();
    for (int off = 1; off < 256; off <<= 1) {
        int w = (t >= off) ? s[t - off] : 0;
        __syncthreads();
        s[t] += w;
        __syncthreads();
    }
    if (t < NBUK) {
        int b = s[t] - v;
        bucket_base[t] = b;
        bucket_cur[t] = b;
    }
}

__global__ __launch_bounds__(256) void scatter_bin(const int* __restrict__ ei,
                                                   int* __restrict__ bucket_cur,
                                                   int2* __restrict__ staging) {
    __shared__ int lcnt[NBUK];
    __shared__ int lrun[NBUK];
    int t = threadIdx.x;
    if (t < NBUK) lcnt[t] = 0;
    __syncthreads();
    int base = blockIdx.x * 4096;
#pragma unroll
    for (int i = 0; i < 16; ++i) {
        int e = base + i * 256 + t;
        if (e < NE) atomicAdd(&lcnt[ei[NE + e] >> 8], 1);
    }
    __syncthreads();
    if (t < NBUK) {
        int c = lcnt[t];
        lrun[t] = c ? atomicAdd(&bucket_cur[t], c) : 0;
        lcnt[t] = 0;
    }
    __syncthreads();
#pragma unroll
    for (int i = 0; i < 16; ++i) {
        int e = base + i * 256 + t;
        if (e < NE) {
            int s = ei[e];
            int d = ei[NE + e];
            int bk = d >> 8;
            int off = atomicAdd(&lcnt[bk], 1);
            staging[lrun[bk] + off] = make_int2(s, e | ((d & 255) << 20));
        }
    }
}

// one block per bucket: LDS node-histogram + scan -> row_beg (global monotone,
// sentinel row_beg[NN]=NE), then LDS-cursor scatter into csrc/cedge.
__global__ __launch_bounds__(256) void place_kernel(
    const int* __restrict__ bucket_base, const int* __restrict__ bucket_cnt,
    const int2* __restrict__ staging, int* __restrict__ row_beg,
    int* __restrict__ csrc, int* __restrict__ cedge) {
    __shared__ int hist[256];
    __shared__ int curp[256];
    int t = threadIdx.x;
    int b = blockIdx.x;
    int n0 = b << 8;
    hist[t] = 0;
    __syncthreads();
    int ebase = bucket_base[b];
    int ecnt = bucket_cnt[b];
    for (int i = t; i < ecnt; i += 256) atomicAdd(&hist[staging[ebase + i].y >> 20], 1);
    __syncthreads();
    int v = hist[t];
    __syncthreads();
    for (int off = 1; off < 256; off <<= 1) {
        int w = (t >= off) ? hist[t - off] : 0;
        __syncthreads();
        hist[t] += w;
        __syncthreads();
    }
    int rb = ebase + hist[t] - v;  // exclusive prefix within bucket
    if (n0 + t < NN) row_beg[n0 + t] = rb;
    if (b == 0 && t == 0) row_beg[NN] = NE;
    curp[t] = rb;
    __syncthreads();
    for (int i = t; i < ecnt; i += 256) {
        int2 p = staging[ebase + i];
        int dl = p.y >> 20;
        int e = p.y & 0xFFFFF;
        int pos = atomicAdd(&curp[dl], 1);
        csrc[pos] = p.x | ((dl & 15) << 20);  // dlocal within 16-node gather block
        cedge[pos] = e;
    }
}

// segaug[v][32] (bf16) = [ segE[v][0..15], deg, 1, 0.. ]
__global__ __launch_bounds__(256) void sege_kernel(
    const int* __restrict__ row_beg, const int* __restrict__ cedge,
    const float* __restrict__ ea, ushort_t* __restrict__ segaug) {
    int node = blockIdx.x * 4 + (threadIdx.x >> 6);
    if (node >= NN) return;
    int lane = threadIdx.x & 63;
    int G = lane >> 2, q4 = (lane & 3) * 4;
    int beg = row_beg[node], end = row_beg[node + 1];
    int dg = end - beg;
    float4 a = make_float4(0.f, 0.f, 0.f, 0.f);
    for (int j = beg + G; j < end; j += 16) {
        int e = cedge[j];
        float4 v = *(const float4*)(ea + (size_t)e * FE + q4);
        a.x += v.x; a.y += v.y; a.z += v.z; a.w += v.w;
    }
    for (int m = 4; m <= 32; m <<= 1) {
        a.x += __shfl_xor(a.x, m);
        a.y += __shfl_xor(a.y, m);
        a.z += __shfl_xor(a.z, m);
        a.w += __shfl_xor(a.w, m);
    }
    if (lane < 4) {
        ushort_t o[4] = {f2bf(a.x), f2bf(a.y), f2bf(a.z), f2bf(a.w)};
        *(uint2*)(segaug + (size_t)node * 32 + lane * 4) = *(uint2*)o;
    } else if (lane < 8) {
        ushort_t o[4] = {0, 0, 0, 0};
        if (lane == 4) { o[0] = f2bf((float)dg); o[1] = f2bf(1.f); }
        *(uint2*)(segaug + (size_t)node * 32 + lane * 4) = *(uint2*)o;
    }
}

// ---------------- weight repack into MFMA B-fragment order ----------------
// 0:W1_msg K64 @0 | 1:W1_self K64 @8192 | 2:eaug1 K32 @16384
// 3..5: Wk_msg K128 @20480+i*16384 | 6..8: eaug_i K32 @69632+i*4096

__global__ void repack_kernel(const float* __restrict__ W1_msg,
                              const float* __restrict__ W1_self,
                              const float* __restrict__ W1_edge,
                              const float* __restrict__ b1_msg,
                              const float* __restrict__ b1_edge,
                              const float* __restrict__ b1_self,
                              const float* __restrict__ Wk_msg,
                              const float* __restrict__ Wk_edge,
                              const float* __restrict__ bk_msg,
                              const float* __restrict__ bk_edge,
                              ushort_t* __restrict__ pack) {
    int mid = blockIdx.y;
    const float *W = nullptr, *bm = nullptr, *be = nullptr, *bc = nullptr;
    int K;
    size_t doff;
    bool aug = false;
    if (mid == 0)      { W = W1_msg;  K = 64;  doff = 0; }
    else if (mid == 1) { W = W1_self; K = 64;  doff = 8192; }
    else if (mid == 2) { W = W1_edge; bm = b1_msg; be = b1_edge; bc = b1_self;
                         K = 32; doff = 16384; aug = true; }
    else if (mid <= 5) { int i = mid - 3; W = Wk_msg + (size_t)i * HD * HD;
                         K = 128; doff = 20480 + (size_t)i * 16384; }
    else               { int i = mid - 6; W = Wk_edge + (size_t)i * FE * HD;
                         bm = bk_msg + i * HD; be = bk_edge + i * HD;
                         K = 32; doff = 69632 + (size_t)i * 4096; aug = true; }
    int KS = K / 32;
    int t = blockIdx.x * 256 + threadIdx.x;
    if (t >= 8 * KS * 64) return;
    int lane = t & 63;
    int nk = t >> 6;
    int ks = nk % KS, nt = nk / KS;
    int n = nt * 16 + (lane & 15);
    int kb = ks * 32 + (lane >> 4) * 8;
    ushort_t o[8];
#pragma unroll
    for (int j = 0; j < 8; ++j) {
        int k = kb + j;
        float v;
        if (!aug)         v = W[(size_t)k * HD + n];
        else if (k < 16)  v = W[(size_t)k * HD + n];
        else if (k == 16) v = bm[n] + be[n];
        else if (k == 17) v = bc ? bc[n] : 0.f;
        else              v = 0.f;
        o[j] = f2bf(v);
    }
    *(uint4*)(pack + doff + (size_t)t * 8) = *(uint4*)o;
}

// ---------------- conv1 GEMM: Cm = x@W1_msg ; Cs = x@W1_self + segaug@eaug1 ----------------

__global__ __launch_bounds__(256) void gemm_mfma_conv1(const float* __restrict__ A,
                                                       const ushort_t* __restrict__ segaug,
                                                       const ushort_t* __restrict__ pack,
                                                       ushort_t* __restrict__ Cm,
                                                       ushort_t* __restrict__ Cs, int n) {
    constexpr int STR = 72, SSTR = 40;
    __shared__ __align__(16) ushort_t As[64 * STR];
    __shared__ __align__(16) ushort_t Ss[64 * SSTR];
    int tid = threadIdx.x;
    int row0 = blockIdx.x * 64;
#pragma unroll
    for (int p = 0; p < 2; ++p) {
        int c = p * 256 + tid;
        int r = c >> 3, col = (c & 7) * 8;
        int gr = row0 + r;
        float4 f0 = make_float4(0.f, 0.f, 0.f, 0.f), f1 = f0;
        if (gr < n) {
            f0 = *(const float4*)(A + (size_t)gr * FN + col);
            f1 = *(const float4*)(A + (size_t)gr * FN + col + 4);
        }
        ushort_t o[8] = {f2bf(f0.x), f2bf(f0.y), f2bf(f0.z), f2bf(f0.w),
                         f2bf(f1.x), f2bf(f1.y), f2bf(f1.z), f2bf(f1.w)};
        *(uint4*)(&As[r * STR + col]) = *(uint4*)o;
    }
    {
        int c = tid;
        int r = c >> 2, col = (c & 3) * 8;
        int gr = row0 + r;
        uint4 v = make_uint4(0u, 0u, 0u, 0u);
        if (gr < n) v = *(const uint4*)(segaug + (size_t)gr * 32 + col);
        *(uint4*)(&Ss[r * SSTR + col]) = v;
    }
    __syncthreads();
    int lane = tid & 63, wave = tid >> 6;
    int m = lane & 15, quad = lane >> 4;
    f32x4 acc[16];
#pragma unroll
    for (int i = 0; i < 16; ++i) acc[i] = (f32x4)(0.f);
    const short8* Bmsg = (const short8*)pack;
    const short8* Bself = (const short8*)(pack + 8192);
    const short8* Beaug = (const short8*)(pack + 16384);
#pragma unroll
    for (int ks = 0; ks < 2; ++ks) {
        short8 a = *(const short8*)(&As[(wave * 16 + m) * STR + ks * 32 + quad * 8]);
#pragma unroll
        for (int nt = 0; nt < 8; ++nt) {
            acc[nt] = __builtin_amdgcn_mfma_f32_16x16x32_bf16(
                a, Bmsg[(nt * 2 + ks) * 64 + lane], acc[nt], 0, 0, 0);
            acc[8 + nt] = __builtin_amdgcn_mfma_f32_16x16x32_bf16(
                a, Bself[(nt * 2 + ks) * 64 + lane], acc[8 + nt], 0, 0, 0);
        }
    }
    {
        short8 sa = *(const short8*)(&Ss[(wave * 16 + m) * SSTR + quad * 8]);
#pragma unroll
        for (int nt = 0; nt < 8; ++nt)
            acc[8 + nt] = __builtin_amdgcn_mfma_f32_16x16x32_bf16(
                sa, Beaug[nt * 64 + lane], acc[8 + nt], 0, 0, 0);
    }
#pragma unroll
    for (int nt = 0; nt < 8; ++nt) {
        int col = nt * 16 + m;
#pragma unroll
        for (int r = 0; r < 4; ++r) {
            int grow = row0 + wave * 16 + quad * 4 + r;
            if (grow < n) {
                Cm[(size_t)grow * HD + col] = f2bf(acc[nt][r]);
                Cs[(size_t)grow * HD + col] = f2bf(acc[8 + nt][r]);
            }
        }
    }
}

// ---------------- fused layer kernel: agg_i + gemm_{i+1} ----------------
// Round-13: edge-balanced gather. Old shape (quarter-wave per NODE, per-node
// loop bounds) wasted ~30% of issue slots on max-of-4-Poisson divergence +
// ragged tails. New shape: block's contiguous edge slice split evenly into
// 16 quarter-wave ranges; same-dst runs accumulate in registers, flush to a
// block f32 LDS accumulator via ds_add (avg ~2 flushes/quarter-wave).

__device__ __forceinline__ void accum8(float* a, uint4 v) {
    a[0] += __uint_as_float(v.x << 16);
    a[1] += __uint_as_float(v.x & 0xffff0000u);
    a[2] += __uint_as_float(v.y << 16);
    a[3] += __uint_as_float(v.y & 0xffff0000u);
    a[4] += __uint_as_float(v.z << 16);
    a[5] += __uint_as_float(v.z & 0xffff0000u);
    a[6] += __uint_as_float(v.w << 16);
    a[7] += __uint_as_float(v.w & 0xffff0000u);
}

#define HP (HD + 4)  // padded f32 row: rows offset 4 banks -> conflict-free reads

// Edge-balanced aggregate of msg rows into hloc[16][HP] (f32, zeroed).
// csrc entries: src | (dlocal16 << 20).
#define EDGE_AGG(hloc)                                                           \
    {                                                                            \
        int qw = tid >> 4;                                                       \
        int epq = (nE + 15) >> 4;                                                \
        int j = b0 + qw * epq;                                                   \
        int qend = b0 + nE;                                                      \
        if (j + epq < qend) qend = j + epq;                                      \
        float a0[8] = {0.f, 0.f, 0.f, 0.f, 0.f, 0.f, 0.f, 0.f};                  \
        int dlcur = -1;                                                          \
        int pn = 0;                                                              \
        uint4 vn = make_uint4(0u, 0u, 0u, 0u);                                   \
        if (j < qend) {                                                          \
            pn = csrc[j];                                                        \
            vn = *(const uint4*)(msg_in + (size_t)(pn & 0xFFFFF) * HD + c8);     \
        }                                                                        \
        while (j < qend) {                                                       \
            int p = pn;                                                          \
            uint4 v = vn;                                                        \
            ++j;                                                                 \
            if (j < qend) {                                                      \
                pn = csrc[j];                                                    \
                vn = *(const uint4*)(msg_in + (size_t)(pn & 0xFFFFF) * HD + c8); \
            }                                                                    \
            int dl = p >> 20;                                                    \
            if (dl != dlcur) {                                                   \
                if (dlcur >= 0) {                                                \
                    float* dst = &hloc[dlcur * HP + c8];                         \
                    _Pragma("unroll") for (int i = 0; i < 8; ++i)                \
                        atomicAdd(dst + i, a0[i]);                               \
                }                                                                \
                _Pragma("unroll") for (int i = 0; i < 8; ++i) a0[i] = 0.f;       \
                dlcur = dl;                                                      \
            }                                                                    \
            accum8(a0, v);                                                       \
        }                                                                        \
        if (dlcur >= 0) {                                                        \
            float* dst = &hloc[dlcur * HP + c8];                                 \
            _Pragma("unroll") for (int i = 0; i < 8; ++i)                        \
                atomicAdd(dst + i, a0[i]);                                       \
        }                                                                        \
    }

__global__ __launch_bounds__(256, 6) void fused_agg_gemm(
    const int* __restrict__ row_beg, const int* __restrict__ csrc,
    const ushort_t* __restrict__ msg_in, const ushort_t* __restrict__ S_in,
    const ushort_t* __restrict__ segaug, const ushort_t* __restrict__ Bm,
    const ushort_t* __restrict__ Be, ushort_t* __restrict__ msg_out,
    ushort_t* __restrict__ S_out) {
    constexpr int STR = 136, SSTR = 40;
    __shared__ __align__(16) ushort_t Hs[16 * STR];
    __shared__ __align__(16) ushort_t Ss[16 * SSTR];
    __shared__ __align__(16) float hloc[16 * HP];
    int tid = threadIdx.x;
    int node0 = blockIdx.x * 16;
    if (tid < 64) {
        int r = tid >> 2, col = (tid & 3) * 8;
        *(uint4*)(&Ss[r * SSTR + col]) =
            *(const uint4*)(segaug + (size_t)(node0 + r) * 32 + col);
    }
#pragma unroll
    for (int i = tid; i < 16 * HP; i += 256) hloc[i] = 0.f;
    int b0 = row_beg[node0];
    int nE = row_beg[node0 + 16] - b0;
    int c8 = (tid & 15) * 8;
    __syncthreads();
    EDGE_AGG(hloc)
    __syncthreads();
    int nl = tid >> 4;
    {
        float s[8] = {0.f, 0.f, 0.f, 0.f, 0.f, 0.f, 0.f, 0.f};
        accum8(s, *(const uint4*)(S_in + (size_t)(node0 + nl) * HD + c8));
        ushort_t h8[8];
#pragma unroll
        for (int i = 0; i < 8; ++i)
            h8[i] = f2bf(fmaxf(hloc[nl * HP + c8 + i] + s[i], 0.f));
        *(uint4*)(&Hs[nl * STR + c8]) = *(uint4*)h8;
    }
    __syncthreads();
    int lane = tid & 63, wave = tid >> 6;
    int m = lane & 15, quad = lane >> 4;
    f32x4 acc[2], accE[2];
#pragma unroll
    for (int t = 0; t < 2; ++t) { acc[t] = (f32x4)(0.f); accE[t] = (f32x4)(0.f); }
    const short8* Bmv = (const short8*)Bm;
    const short8* Bev = (const short8*)Be;
#pragma unroll
    for (int ks = 0; ks < 4; ++ks) {
        short8 a = *(const short8*)(&Hs[m * STR + ks * 32 + quad * 8]);
#pragma unroll
        for (int t = 0; t < 2; ++t) {
            int nt = wave * 2 + t;
            acc[t] = __builtin_amdgcn_mfma_f32_16x16x32_bf16(
                a, Bmv[(nt * 4 + ks) * 64 + lane], acc[t], 0, 0, 0);
        }
    }
    {
        short8 sa = *(const short8*)(&Ss[m * SSTR + quad * 8]);
#pragma unroll
        for (int t = 0; t < 2; ++t) {
            int nt = wave * 2 + t;
            accE[t] = __builtin_amdgcn_mfma_f32_16x16x32_bf16(
                sa, Bev[nt * 64 + lane], accE[t], 0, 0, 0);
        }
    }
#pragma unroll
    for (int t = 0; t < 2; ++t) {
        int col = (wave * 2 + t) * 16 + m;
#pragma unroll
        for (int r = 0; r < 4; ++r) {
            int rl = quad * 4 + r;
            size_t gidx = (size_t)(node0 + rl) * HD + col;
            msg_out[gidx] = f2bf(acc[t][r]);
            S_out[gidx] = f2bf(accE[t][r] + bf2f(Hs[rl * STR + col]));
        }
    }
}

// ---------------- final aggregate fused with pooling ----------------
// h4 = relu(gather + S) is consumed ONLY by mean-pool -> never write it to
// global. Round-13 edge-balanced gather, f32 accumulation directly in hloc.

__global__ __launch_bounds__(256, 6) void agg_pool_kernel(
    const int* __restrict__ row_beg, const int* __restrict__ csrc,
    const ushort_t* __restrict__ msg_in, const ushort_t* __restrict__ selfb,
    const int* __restrict__ batch, float* __restrict__ pooled) {
    __shared__ __align__(16) float hloc[16 * HP];
    int tid = threadIdx.x;
    int node0 = blockIdx.x * 16;
#pragma unroll
    for (int i = tid; i < 16 * HP; i += 256) hloc[i] = 0.f;
    int b0 = row_beg[node0];
    int nE = row_beg[node0 + 16] - b0;
    int c8 = (tid & 15) * 8;
    __syncthreads();
    EDGE_AGG(hloc)
    __syncthreads();
    int nl = tid >> 4;
    {
        float s[8] = {0.f, 0.f, 0.f, 0.f, 0.f, 0.f, 0.f, 0.f};
        accum8(s, *(const uint4*)(selfb + (size_t)(node0 + nl) * HD + c8));
#pragma unroll
        for (int i = 0; i < 8; ++i)
            hloc[nl * HP + c8 + i] = fmaxf(hloc[nl * HP + c8 + i] + s[i], 0.f);
    }
    __syncthreads();
    if (tid < HD) {
        int f = tid;
        float run = 0.f;
        int gprev = batch[node0];
        for (int r = 0; r < 16; ++r) {
            int g = batch[node0 + r];
            if (g != gprev) {
                atomicAdd(&pooled[gprev * HD + f], run);
                run = 0.f;
                gprev = g;
            }
            run += hloc[r * HP + f];
        }
        atomicAdd(&pooled[gprev * HD + f], run);
    }
}

// ---------------- fusion head (reads completed pooled sums) ----------------

__global__ void head_kernel(const float* __restrict__ pooled, const int* __restrict__ batch,
                            const float* __restrict__ lf, const float* __restrict__ pfe,
                            const float* __restrict__ Wl, const float* __restrict__ bl,
                            const float* __restrict__ Wp, const float* __restrict__ bp,
                            const float* __restrict__ Wf, const float* __restrict__ bfv,
                            const float* __restrict__ Wo, const float* __restrict__ bo,
                            float* __restrict__ out) {
    __shared__ float cat[3 * HD];
    __shared__ float red[HD];
    int g = blockIdx.x, j = threadIdx.x;
    int lo = 0, hi = NN;
    while (lo < hi) { int m = (lo + hi) >> 1; if (batch[m] < g) lo = m + 1; else hi = m; }
    int s0 = lo;
    lo = s0; hi = NN;
    while (lo < hi) { int m = (lo + hi) >> 1; if (batch[m] < g + 1) lo = m + 1; else hi = m; }
    float cntf = (float)(lo - s0);
    cat[j] = pooled[(size_t)g * HD + j] / fmaxf(cntf, 1.f);
    float s = bl[j];
    for (int k = 0; k < FL; ++k) s += lf[g * FL + k] * Wl[k * HD + j];
    cat[HD + j] = s;
    s = bp[j];
    for (int k = 0; k < FPOC; ++k) s += pfe[g * FPOC + k] * Wp[k * HD + j];
    cat[2 * HD + j] = s;
    __syncthreads();
    float fj = bfv[j];
    for (int k = 0; k < 3 * HD; ++k) fj += cat[k] * Wf[k * HD + j];
    red[j] = fj * Wo[j];
    __syncthreads();
    for (int off = 64; off > 0; off >>= 1) {
        if (j < off) red[j] += red[j + off];
        __syncthreads();
    }
    if (j == 0) out[g] = red[0] + bo[0];
}

// ---------------- launch ----------------

extern "C" void kernel_launch(void* const* d_in, const int* in_sizes, int n_in,
                              void* d_out, int out_size, void* d_ws, size_t ws_size,
                              hipStream_t stream) {
    const float* x       = (const float*)d_in[0];
    const int*   ei      = (const int*)d_in[1];
    const float* ea      = (const float*)d_in[2];
    const int*   batch   = (const int*)d_in[3];
    const float* lf      = (const float*)d_in[4];
    const float* pfe     = (const float*)d_in[5];
    const float* W1_msg  = (const float*)d_in[6];
    const float* b1_msg  = (const float*)d_in[7];
    const float* W1_edge = (const float*)d_in[8];
    const float* b1_edge = (const float*)d_in[9];
    const float* W1_self = (const float*)d_in[10];
    const float* b1_self = (const float*)d_in[11];
    const float* Wk_msg  = (const float*)d_in[12];
    const float* bk_msg  = (const float*)d_in[13];
    const float* Wk_edge = (const float*)d_in[14];
    const float* bk_edge = (const float*)d_in[15];
    const float* Wl      = (const float*)d_in[16];
    const float* bl      = (const float*)d_in[17];
    const float* Wp      = (const float*)d_in[18];
    const float* bp      = (const float*)d_in[19];
    const float* Wf      = (const float*)d_in[20];
    const float* bfv     = (const float*)d_in[21];
    const float* Wo      = (const float*)d_in[22];
    const float* bo      = (const float*)d_in[23];

    char* wsp = (char*)d_ws;
    size_t off = 0;
    auto carve = [&](size_t bytes) -> void* {
        char* p = wsp + off;
        off += (bytes + 255) & ~(size_t)255;
        return (void*)p;
    };
    // zeroed span: bucket_cnt .. pooled (contiguous carves)
    int*      bucket_cnt  = (int*)carve((size_t)NBUK * 4);
    float*    pooled      = (float*)carve((size_t)NG * HD * 4);
    int*      bucket_base = (int*)carve((size_t)NBUK * 4);
    int*      bucket_cur  = (int*)carve((size_t)NBUK * 4);
    int*      row_beg     = (int*)carve((size_t)(NN + 1) * 4);
    int2*     staging     = (int2*)carve((size_t)NE * 8);
    int*      csrc        = (int*)carve((size_t)NE * 4);
    int*      cedge       = (int*)carve((size_t)NE * 4);
    ushort_t* segaug      = (ushort_t*)carve((size_t)NN * 32 * 2);
    ushort_t* pack        = (ushort_t*)carve((size_t)81920 * 2);
    ushort_t* bufC        = (ushort_t*)carve((size_t)NN * HD * 2);  // msg ping
    ushort_t* bufD        = (ushort_t*)carve((size_t)NN * HD * 2);  // msg pong
    ushort_t* bufS        = (ushort_t*)carve((size_t)NN * HD * 2);  // S ping
    ushort_t* bufT        = (ushort_t*)carve((size_t)NN * HD * 2);  // S pong

    size_t clr = (size_t)((char*)(pooled + NG * HD) - (char*)bucket_cnt);
    hipMemsetAsync(bucket_cnt, 0, clr, stream);

    hist_kernel<<<(NE + 2047) / 2048, 256, 0, stream>>>(ei, bucket_cnt);
    scan_kernel<<<1, 256, 0, stream>>>(bucket_cnt, bucket_base, bucket_cur);
    scatter_bin<<<(NE + 4095) / 4096, 256, 0, stream>>>(ei, bucket_cur, staging);
    place_kernel<<<NBUK, 256, 0, stream>>>(bucket_base, bucket_cnt, staging, row_beg,
                                           csrc, cedge);
    sege_kernel<<<(NN + 3) / 4, 256, 0, stream>>>(row_beg, cedge, ea, segaug);
    repack_kernel<<<dim3(8, 9), 256, 0, stream>>>(W1_msg, W1_self, W1_edge, b1_msg,
                                                  b1_edge, b1_self, Wk_msg, Wk_edge,
                                                  bk_msg, bk_edge, pack);

    // conv1: msg1 -> bufC, S1 = x@W1_self + edge-term -> bufS
    gemm_mfma_conv1<<<dim3((NN + 63) / 64), 256, 0, stream>>>(x, segaug, pack, bufC,
                                                              bufS, NN);
    // fused layers (h stays on-chip)
    fused_agg_gemm<<<NN / 16, 256, 0, stream>>>(row_beg, csrc, bufC, bufS, segaug,
                                                pack + 20480, pack + 69632, bufD, bufT);
    fused_agg_gemm<<<NN / 16, 256, 0, stream>>>(row_beg, csrc, bufD, bufT, segaug,
                                                pack + 20480 + 16384, pack + 69632 + 4096,
                                                bufC, bufS);
    fused_agg_gemm<<<NN / 16, 256, 0, stream>>>(row_beg, csrc, bufC, bufS, segaug,
                                                pack + 20480 + 32768, pack + 69632 + 8192,
                                                bufD, bufT);
    // final agg fused with mean-pool accumulation (h4 never hits global)
    agg_pool_kernel<<<NN / 16, 256, 0, stream>>>(row_beg, csrc, bufD, bufT, batch,
                                                 pooled);

    head_kernel<<<NG, HD, 0, stream>>>(pooled, batch, lf, pfe, Wl, bl, Wp, bp, Wf, bfv,
                                       Wo, bo, (float*)d_out);
}

// Round 5
// 409.478 us; speedup vs baseline: 1.3204x; 1.3204x over previous
//
#include <hip/hip_runtime.h>
#include <cstdint>

#define NN 50000
#define NE 640000
#define NG 128
#define HD 128
#define FN 64
#define FE 16
#define FL 200
#define FPOC 100
#define NSTACK 3
#define NBUK 196  // ceil(NN/256): dst-buckets of 256 nodes; bucket = d>>8

typedef unsigned short ushort_t;
typedef short short8 __attribute__((ext_vector_type(8)));
typedef float f32x4 __attribute__((ext_vector_type(4)));

__device__ __forceinline__ ushort_t f2bf(float f) {
    unsigned u = __float_as_uint(f);
    unsigned r = (u + 0x7fffu + ((u >> 16) & 1u)) >> 16;
    return (ushort_t)r;
}
__device__ __forceinline__ float bf2f(ushort_t u) {
    return __uint_as_float(((unsigned)u) << 16);
}

// ---------------- CSR build (round-12 bucketed scatter; proven) ----------------
// Round-1 rocprof: direct int2 scatter = 48us, 42.5MB writes for a 5.1MB csr
// (cross-XCD line re-dirtying). Two-level bucketed scatter fixed it (397->357).
// csrc (src, 4B) / cedge (edge id, 4B) split halves gather index traffic.
// GATHER NOTE (rounds 1/3 post-mortems): per-node quarter-wave with unroll-4+
// in-flight gathers is the proven shape. Edge-balanced ILP-1 regressed 52%
// (latency-serialized); LDS csr staging + occ-5 was neutral. Gather limiter
// is the random-line fetch path, NOT VMEM instruction issue.
// Round-15 = round-14 resubmitted verbatim (infra failure, never measured).

__global__ void hist_kernel(const int* __restrict__ ei, int* __restrict__ bucket_cnt) {
    __shared__ int l[NBUK];
    int t = threadIdx.x;
    if (t < NBUK) l[t] = 0;
    __syncthreads();
    int base = blockIdx.x * 2048;
#pragma unroll
    for (int i = 0; i < 8; ++i) {
        int e = base + i * 256 + t;
        if (e < NE) atomicAdd(&l[ei[NE + e] >> 8], 1);
    }
    __syncthreads();
    if (t < NBUK && l[t]) atomicAdd(&bucket_cnt[t], l[t]);
}

__global__ void scan_kernel(const int* __restrict__ bucket_cnt,
                            int* __restrict__ bucket_base, int* __restrict__ bucket_cur) {
    __shared__ int s[256];
    int t = threadIdx.x;
    int v = (t < NBUK) ? bucket_cnt[t] : 0;
    s[t] = v;
    __syncthreads();
    for (int off = 1; off < 256; off <<= 1) {
        int w = (t >= off) ? s[t - off] : 0;
        __syncthreads();
        s[t] += w;
        __syncthreads();
    }
    if (t < NBUK) {
        int b = s[t] - v;
        bucket_base[t] = b;
        bucket_cur[t] = b;
    }
}

__global__ __launch_bounds__(256) void scatter_bin(const int* __restrict__ ei,
                                                   int* __restrict__ bucket_cur,
                                                   int2* __restrict__ staging) {
    __shared__ int lcnt[NBUK];
    __shared__ int lrun[NBUK];
    int t = threadIdx.x;
    if (t < NBUK) lcnt[t] = 0;
    __syncthreads();
    int base = blockIdx.x * 4096;
#pragma unroll
    for (int i = 0; i < 16; ++i) {
        int e = base + i * 256 + t;
        if (e < NE) atomicAdd(&lcnt[ei[NE + e] >> 8], 1);
    }
    __syncthreads();
    if (t < NBUK) {
        int c = lcnt[t];
        lrun[t] = c ? atomicAdd(&bucket_cur[t], c) : 0;
        lcnt[t] = 0;
    }
    __syncthreads();
#pragma unroll
    for (int i = 0; i < 16; ++i) {
        int e = base + i * 256 + t;
        if (e < NE) {
            int s = ei[e];
            int d = ei[NE + e];
            int bk = d >> 8;
            int off = atomicAdd(&lcnt[bk], 1);
            staging[lrun[bk] + off] = make_int2(s, e | ((d & 255) << 20));
        }
    }
}

// one block per bucket: LDS node-histogram + scan -> row_beg (global monotone,
// sentinel row_beg[NN]=NE), then LDS-cursor scatter into csrc/cedge.
__global__ __launch_bounds__(256) void place_kernel(
    const int* __restrict__ bucket_base, const int* __restrict__ bucket_cnt,
    const int2* __restrict__ staging, int* __restrict__ row_beg,
    int* __restrict__ csrc, int* __restrict__ cedge) {
    __shared__ int hist[256];
    __shared__ int curp[256];
    int t = threadIdx.x;
    int b = blockIdx.x;
    int n0 = b << 8;
    hist[t] = 0;
    __syncthreads();
    int ebase = bucket_base[b];
    int ecnt = bucket_cnt[b];
    for (int i = t; i < ecnt; i += 256) atomicAdd(&hist[staging[ebase + i].y >> 20], 1);
    __syncthreads();
    int v = hist[t];
    __syncthreads();
    for (int off = 1; off < 256; off <<= 1) {
        int w = (t >= off) ? hist[t - off] : 0;
        __syncthreads();
        hist[t] += w;
        __syncthreads();
    }
    int rb = ebase + hist[t] - v;  // exclusive prefix within bucket
    if (n0 + t < NN) row_beg[n0 + t] = rb;
    if (b == 0 && t == 0) row_beg[NN] = NE;
    curp[t] = rb;
    __syncthreads();
    for (int i = t; i < ecnt; i += 256) {
        int2 p = staging[ebase + i];
        int dl = p.y >> 20;
        int e = p.y & 0xFFFFF;
        int pos = atomicAdd(&curp[dl], 1);
        csrc[pos] = p.x;
        cedge[pos] = e;
    }
}

// segaug[v][32] (bf16) = [ segE[v][0..15], deg, 1, 0.. ]
__global__ __launch_bounds__(256) void sege_kernel(
    const int* __restrict__ row_beg, const int* __restrict__ cedge,
    const float* __restrict__ ea, ushort_t* __restrict__ segaug) {
    int node = blockIdx.x * 4 + (threadIdx.x >> 6);
    if (node >= NN) return;
    int lane = threadIdx.x & 63;
    int G = lane >> 2, q4 = (lane & 3) * 4;
    int beg = row_beg[node], end = row_beg[node + 1];
    int dg = end - beg;
    float4 a = make_float4(0.f, 0.f, 0.f, 0.f);
    for (int j = beg + G; j < end; j += 16) {
        int e = cedge[j];
        float4 v = *(const float4*)(ea + (size_t)e * FE + q4);
        a.x += v.x; a.y += v.y; a.z += v.z; a.w += v.w;
    }
    for (int m = 4; m <= 32; m <<= 1) {
        a.x += __shfl_xor(a.x, m);
        a.y += __shfl_xor(a.y, m);
        a.z += __shfl_xor(a.z, m);
        a.w += __shfl_xor(a.w, m);
    }
    if (lane < 4) {
        ushort_t o[4] = {f2bf(a.x), f2bf(a.y), f2bf(a.z), f2bf(a.w)};
        *(uint2*)(segaug + (size_t)node * 32 + lane * 4) = *(uint2*)o;
    } else if (lane < 8) {
        ushort_t o[4] = {0, 0, 0, 0};
        if (lane == 4) { o[0] = f2bf((float)dg); o[1] = f2bf(1.f); }
        *(uint2*)(segaug + (size_t)node * 32 + lane * 4) = *(uint2*)o;
    }
}

// ---------------- weight repack into MFMA B-fragment order ----------------
// 0:W1_msg K64 @0 | 1:W1_self K64 @8192 | 2:eaug1 K32 @16384
// 3..5: Wk_msg K128 @20480+i*16384 | 6..8: eaug_i K32 @69632+i*4096

__global__ void repack_kernel(const float* __restrict__ W1_msg,
                              const float* __restrict__ W1_self,
                              const float* __restrict__ W1_edge,
                              const float* __restrict__ b1_msg,
                              const float* __restrict__ b1_edge,
                              const float* __restrict__ b1_self,
                              const float* __restrict__ Wk_msg,
                              const float* __restrict__ Wk_edge,
                              const float* __restrict__ bk_msg,
                              const float* __restrict__ bk_edge,
                              ushort_t* __restrict__ pack) {
    int mid = blockIdx.y;
    const float *W = nullptr, *bm = nullptr, *be = nullptr, *bc = nullptr;
    int K;
    size_t doff;
    bool aug = false;
    if (mid == 0)      { W = W1_msg;  K = 64;  doff = 0; }
    else if (mid == 1) { W = W1_self; K = 64;  doff = 8192; }
    else if (mid == 2) { W = W1_edge; bm = b1_msg; be = b1_edge; bc = b1_self;
                         K = 32; doff = 16384; aug = true; }
    else if (mid <= 5) { int i = mid - 3; W = Wk_msg + (size_t)i * HD * HD;
                         K = 128; doff = 20480 + (size_t)i * 16384; }
    else               { int i = mid - 6; W = Wk_edge + (size_t)i * FE * HD;
                         bm = bk_msg + i * HD; be = bk_edge + i * HD;
                         K = 32; doff = 69632 + (size_t)i * 4096; aug = true; }
    int KS = K / 32;
    int t = blockIdx.x * 256 + threadIdx.x;
    if (t >= 8 * KS * 64) return;
    int lane = t & 63;
    int nk = t >> 6;
    int ks = nk % KS, nt = nk / KS;
    int n = nt * 16 + (lane & 15);
    int kb = ks * 32 + (lane >> 4) * 8;
    ushort_t o[8];
#pragma unroll
    for (int j = 0; j < 8; ++j) {
        int k = kb + j;
        float v;
        if (!aug)         v = W[(size_t)k * HD + n];
        else if (k < 16)  v = W[(size_t)k * HD + n];
        else if (k == 16) v = bm[n] + be[n];
        else if (k == 17) v = bc ? bc[n] : 0.f;
        else              v = 0.f;
        o[j] = f2bf(v);
    }
    *(uint4*)(pack + doff + (size_t)t * 8) = *(uint4*)o;
}

// ---------------- conv1 GEMM: Cm = x@W1_msg ; Cs = x@W1_self + segaug@eaug1 ----------------

__global__ __launch_bounds__(256) void gemm_mfma_conv1(const float* __restrict__ A,
                                                       const ushort_t* __restrict__ segaug,
                                                       const ushort_t* __restrict__ pack,
                                                       ushort_t* __restrict__ Cm,
                                                       ushort_t* __restrict__ Cs, int n) {
    constexpr int STR = 72, SSTR = 40;
    __shared__ __align__(16) ushort_t As[64 * STR];
    __shared__ __align__(16) ushort_t Ss[64 * SSTR];
    int tid = threadIdx.x;
    int row0 = blockIdx.x * 64;
#pragma unroll
    for (int p = 0; p < 2; ++p) {
        int c = p * 256 + tid;
        int r = c >> 3, col = (c & 7) * 8;
        int gr = row0 + r;
        float4 f0 = make_float4(0.f, 0.f, 0.f, 0.f), f1 = f0;
        if (gr < n) {
            f0 = *(const float4*)(A + (size_t)gr * FN + col);
            f1 = *(const float4*)(A + (size_t)gr * FN + col + 4);
        }
        ushort_t o[8] = {f2bf(f0.x), f2bf(f0.y), f2bf(f0.z), f2bf(f0.w),
                         f2bf(f1.x), f2bf(f1.y), f2bf(f1.z), f2bf(f1.w)};
        *(uint4*)(&As[r * STR + col]) = *(uint4*)o;
    }
    {
        int c = tid;
        int r = c >> 2, col = (c & 3) * 8;
        int gr = row0 + r;
        uint4 v = make_uint4(0u, 0u, 0u, 0u);
        if (gr < n) v = *(const uint4*)(segaug + (size_t)gr * 32 + col);
        *(uint4*)(&Ss[r * SSTR + col]) = v;
    }
    __syncthreads();
    int lane = tid & 63, wave = tid >> 6;
    int m = lane & 15, quad = lane >> 4;
    f32x4 acc[16];
#pragma unroll
    for (int i = 0; i < 16; ++i) acc[i] = (f32x4)(0.f);
    const short8* Bmsg = (const short8*)pack;
    const short8* Bself = (const short8*)(pack + 8192);
    const short8* Beaug = (const short8*)(pack + 16384);
#pragma unroll
    for (int ks = 0; ks < 2; ++ks) {
        short8 a = *(const short8*)(&As[(wave * 16 + m) * STR + ks * 32 + quad * 8]);
#pragma unroll
        for (int nt = 0; nt < 8; ++nt) {
            acc[nt] = __builtin_amdgcn_mfma_f32_16x16x32_bf16(
                a, Bmsg[(nt * 2 + ks) * 64 + lane], acc[nt], 0, 0, 0);
            acc[8 + nt] = __builtin_amdgcn_mfma_f32_16x16x32_bf16(
                a, Bself[(nt * 2 + ks) * 64 + lane], acc[8 + nt], 0, 0, 0);
        }
    }
    {
        short8 sa = *(const short8*)(&Ss[(wave * 16 + m) * SSTR + quad * 8]);
#pragma unroll
        for (int nt = 0; nt < 8; ++nt)
            acc[8 + nt] = __builtin_amdgcn_mfma_f32_16x16x32_bf16(
                sa, Beaug[nt * 64 + lane], acc[8 + nt], 0, 0, 0);
    }
#pragma unroll
    for (int nt = 0; nt < 8; ++nt) {
        int col = nt * 16 + m;
#pragma unroll
        for (int r = 0; r < 4; ++r) {
            int grow = row0 + wave * 16 + quad * 4 + r;
            if (grow < n) {
                Cm[(size_t)grow * HD + col] = f2bf(acc[nt][r]);
                Cs[(size_t)grow * HD + col] = f2bf(acc[8 + nt][r]);
            }
        }
    }
}

// ---------------- fused layer kernel: agg_i + gemm_{i+1} ----------------
// Round-14/15: proven round-2 gather shape (per-node quarter-wave, occ 6) with
// (a) csrc 4B index stream, (b) row_beg sentinel (no cnt array), and
// (c) unroll-8 main loop — ILP-8 at occupancy 6 (untested combination;
// round-1 only tested ILP-8 at occ-5 + LDS staging).

__device__ __forceinline__ void accum8(float* a, uint4 v) {
    a[0] += __uint_as_float(v.x << 16);
    a[1] += __uint_as_float(v.x & 0xffff0000u);
    a[2] += __uint_as_float(v.y << 16);
    a[3] += __uint_as_float(v.y & 0xffff0000u);
    a[4] += __uint_as_float(v.z << 16);
    a[5] += __uint_as_float(v.z & 0xffff0000u);
    a[6] += __uint_as_float(v.w << 16);
    a[7] += __uint_as_float(v.w & 0xffff0000u);
}

#define AGG_LOOP(SRCBUF)                                                      \
    {                                                                         \
        int j = beg;                                                          \
        for (; j + 7 < end; j += 8) {                                         \
            int u[8];                                                         \
            _Pragma("unroll") for (int t = 0; t < 8; ++t) u[t] = csrc[j + t]; \
            uint4 v[8];                                                       \
            _Pragma("unroll") for (int t = 0; t < 8; ++t)                     \
                v[t] = *(const uint4*)(SRCBUF + (size_t)u[t] * HD + c8);      \
            _Pragma("unroll") for (int t = 0; t < 8; ++t)                     \
                accum8((t & 1) ? a1 : a0, v[t]);                              \
        }                                                                     \
        if (j + 3 < end) {                                                    \
            int u[4];                                                         \
            _Pragma("unroll") for (int t = 0; t < 4; ++t) u[t] = csrc[j + t]; \
            uint4 v[4];                                                       \
            _Pragma("unroll") for (int t = 0; t < 4; ++t)                     \
                v[t] = *(const uint4*)(SRCBUF + (size_t)u[t] * HD + c8);      \
            _Pragma("unroll") for (int t = 0; t < 4; ++t)                     \
                accum8((t & 1) ? a1 : a0, v[t]);                              \
            j += 4;                                                           \
        }                                                                     \
        for (; j < end; ++j) {                                                \
            uint4 v = *(const uint4*)(SRCBUF + (size_t)csrc[j] * HD + c8);    \
            accum8(a0, v);                                                    \
        }                                                                     \
    }

__global__ __launch_bounds__(256, 6) void fused_agg_gemm(
    const int* __restrict__ row_beg, const int* __restrict__ csrc,
    const ushort_t* __restrict__ msg_in, const ushort_t* __restrict__ S_in,
    const ushort_t* __restrict__ segaug, const ushort_t* __restrict__ Bm,
    const ushort_t* __restrict__ Be, ushort_t* __restrict__ msg_out,
    ushort_t* __restrict__ S_out) {
    constexpr int STR = 136, SSTR = 40;
    __shared__ __align__(16) ushort_t Hs[16 * STR];
    __shared__ __align__(16) ushort_t Ss[16 * SSTR];
    int tid = threadIdx.x;
    int node0 = blockIdx.x * 16;
    if (tid < 64) {
        int r = tid >> 2, col = (tid & 3) * 8;
        *(uint4*)(&Ss[r * SSTR + col]) =
            *(const uint4*)(segaug + (size_t)(node0 + r) * 32 + col);
    }
    int nl = tid >> 4;
    int node = node0 + nl;
    int c8 = (tid & 15) * 8;
    int beg = row_beg[node];
    int end = row_beg[node + 1];
    float a0[8] = {0.f, 0.f, 0.f, 0.f, 0.f, 0.f, 0.f, 0.f};
    float a1[8] = {0.f, 0.f, 0.f, 0.f, 0.f, 0.f, 0.f, 0.f};
    AGG_LOOP(msg_in)
    accum8(a0, *(const uint4*)(S_in + (size_t)node * HD + c8));
    {
        ushort_t h8[8];
#pragma unroll
        for (int i = 0; i < 8; ++i) h8[i] = f2bf(fmaxf(a0[i] + a1[i], 0.f));
        *(uint4*)(&Hs[nl * STR + c8]) = *(uint4*)h8;
    }
    __syncthreads();
    int lane = tid & 63, wave = tid >> 6;
    int m = lane & 15, quad = lane >> 4;
    f32x4 acc[2], accE[2];
#pragma unroll
    for (int t = 0; t < 2; ++t) { acc[t] = (f32x4)(0.f); accE[t] = (f32x4)(0.f); }
    const short8* Bmv = (const short8*)Bm;
    const short8* Bev = (const short8*)Be;
#pragma unroll
    for (int ks = 0; ks < 4; ++ks) {
        short8 a = *(const short8*)(&Hs[m * STR + ks * 32 + quad * 8]);
#pragma unroll
        for (int t = 0; t < 2; ++t) {
            int nt = wave * 2 + t;
            acc[t] = __builtin_amdgcn_mfma_f32_16x16x32_bf16(
                a, Bmv[(nt * 4 + ks) * 64 + lane], acc[t], 0, 0, 0);
        }
    }
    {
        short8 sa = *(const short8*)(&Ss[m * SSTR + quad * 8]);
#pragma unroll
        for (int t = 0; t < 2; ++t) {
            int nt = wave * 2 + t;
            accE[t] = __builtin_amdgcn_mfma_f32_16x16x32_bf16(
                sa, Bev[nt * 64 + lane], accE[t], 0, 0, 0);
        }
    }
#pragma unroll
    for (int t = 0; t < 2; ++t) {
        int col = (wave * 2 + t) * 16 + m;
#pragma unroll
        for (int r = 0; r < 4; ++r) {
            int rl = quad * 4 + r;
            size_t gidx = (size_t)(node0 + rl) * HD + col;
            msg_out[gidx] = f2bf(acc[t][r]);
            S_out[gidx] = f2bf(accE[t][r] + bf2f(Hs[rl * STR + col]));
        }
    }
}

// ---------------- final aggregate fused with pooling ----------------
// h4 = relu(gather + S) is consumed ONLY by mean-pool -> never write it to
// global. Round-2 gather shape + round-14 index split/unroll-8.

__global__ __launch_bounds__(256, 6) void agg_pool_kernel(
    const int* __restrict__ row_beg, const int* __restrict__ csrc,
    const ushort_t* __restrict__ xm, const ushort_t* __restrict__ selfb,
    const int* __restrict__ batch, float* __restrict__ pooled) {
    __shared__ float hloc[16][HD];
    int tid = threadIdx.x;
    int node0 = blockIdx.x * 16;
    int nl = tid >> 4;
    int node = node0 + nl;
    int c8 = (tid & 15) * 8;
    int beg = row_beg[node];
    int end = row_beg[node + 1];
    float a0[8] = {0.f, 0.f, 0.f, 0.f, 0.f, 0.f, 0.f, 0.f};
    float a1[8] = {0.f, 0.f, 0.f, 0.f, 0.f, 0.f, 0.f, 0.f};
    AGG_LOOP(xm)
    accum8(a0, *(const uint4*)(selfb + (size_t)node * HD + c8));
#pragma unroll
    for (int i = 0; i < 8; ++i) hloc[nl][c8 + i] = fmaxf(a0[i] + a1[i], 0.f);
    __syncthreads();
    if (tid < HD) {
        int f = tid;
        float run = 0.f;
        int gprev = batch[node0];
        for (int r = 0; r < 16; ++r) {
            int g = batch[node0 + r];
            if (g != gprev) {
                atomicAdd(&pooled[gprev * HD + f], run);
                run = 0.f;
                gprev = g;
            }
            run += hloc[r][f];
        }
        atomicAdd(&pooled[gprev * HD + f], run);
    }
}

// ---------------- fusion head (reads completed pooled sums) ----------------

__global__ void head_kernel(const float* __restrict__ pooled, const int* __restrict__ batch,
                            const float* __restrict__ lf, const float* __restrict__ pfe,
                            const float* __restrict__ Wl, const float* __restrict__ bl,
                            const float* __restrict__ Wp, const float* __restrict__ bp,
                            const float* __restrict__ Wf, const float* __restrict__ bfv,
                            const float* __restrict__ Wo, const float* __restrict__ bo,
                            float* __restrict__ out) {
    __shared__ float cat[3 * HD];
    __shared__ float red[HD];
    int g = blockIdx.x, j = threadIdx.x;
    int lo = 0, hi = NN;
    while (lo < hi) { int m = (lo + hi) >> 1; if (batch[m] < g) lo = m + 1; else hi = m; }
    int s0 = lo;
    lo = s0; hi = NN;
    while (lo < hi) { int m = (lo + hi) >> 1; if (batch[m] < g + 1) lo = m + 1; else hi = m; }
    float cntf = (float)(lo - s0);
    cat[j] = pooled[(size_t)g * HD + j] / fmaxf(cntf, 1.f);
    float s = bl[j];
    for (int k = 0; k < FL; ++k) s += lf[g * FL + k] * Wl[k * HD + j];
    cat[HD + j] = s;
    s = bp[j];
    for (int k = 0; k < FPOC; ++k) s += pfe[g * FPOC + k] * Wp[k * HD + j];
    cat[2 * HD + j] = s;
    __syncthreads();
    float fj = bfv[j];
    for (int k = 0; k < 3 * HD; ++k) fj += cat[k] * Wf[k * HD + j];
    red[j] = fj * Wo[j];
    __syncthreads();
    for (int off = 64; off > 0; off >>= 1) {
        if (j < off) red[j] += red[j + off];
        __syncthreads();
    }
    if (j == 0) out[g] = red[0] + bo[0];
}

// ---------------- launch ----------------

extern "C" void kernel_launch(void* const* d_in, const int* in_sizes, int n_in,
                              void* d_out, int out_size, void* d_ws, size_t ws_size,
                              hipStream_t stream) {
    const float* x       = (const float*)d_in[0];
    const int*   ei      = (const int*)d_in[1];
    const float* ea      = (const float*)d_in[2];
    const int*   batch   = (const int*)d_in[3];
    const float* lf      = (const float*)d_in[4];
    const float* pfe     = (const float*)d_in[5];
    const float* W1_msg  = (const float*)d_in[6];
    const float* b1_msg  = (const float*)d_in[7];
    const float* W1_edge = (const float*)d_in[8];
    const float* b1_edge = (const float*)d_in[9];
    const float* W1_self = (const float*)d_in[10];
    const float* b1_self = (const float*)d_in[11];
    const float* Wk_msg  = (const float*)d_in[12];
    const float* bk_msg  = (const float*)d_in[13];
    const float* Wk_edge = (const float*)d_in[14];
    const float* bk_edge = (const float*)d_in[15];
    const float* Wl      = (const float*)d_in[16];
    const float* bl      = (const float*)d_in[17];
    const float* Wp      = (const float*)d_in[18];
    const float* bp      = (const float*)d_in[19];
    const float* Wf      = (const float*)d_in[20];
    const float* bfv     = (const float*)d_in[21];
    const float* Wo      = (const float*)d_in[22];
    const float* bo      = (const float*)d_in[23];

    char* wsp = (char*)d_ws;
    size_t off = 0;
    auto carve = [&](size_t bytes) -> void* {
        char* p = wsp + off;
        off += (bytes + 255) & ~(size_t)255;
        return (void*)p;
    };
    // zeroed span: bucket_cnt .. pooled (contiguous carves)
    int*      bucket_cnt  = (int*)carve((size_t)NBUK * 4);
    float*    pooled      = (float*)carve((size_t)NG * HD * 4);
    int*      bucket_base = (int*)carve((size_t)NBUK * 4);
    int*      bucket_cur  = (int*)carve((size_t)NBUK * 4);
    int*      row_beg     = (int*)carve((size_t)(NN + 1) * 4);
    int2*     staging     = (int2*)carve((size_t)NE * 8);
    int*      csrc        = (int*)carve((size_t)NE * 4);
    int*      cedge       = (int*)carve((size_t)NE * 4);
    ushort_t* segaug      = (ushort_t*)carve((size_t)NN * 32 * 2);
    ushort_t* pack        = (ushort_t*)carve((size_t)81920 * 2);
    ushort_t* bufC        = (ushort_t*)carve((size_t)NN * HD * 2);  // msg ping
    ushort_t* bufD        = (ushort_t*)carve((size_t)NN * HD * 2);  // msg pong
    ushort_t* bufS        = (ushort_t*)carve((size_t)NN * HD * 2);  // S ping
    ushort_t* bufT        = (ushort_t*)carve((size_t)NN * HD * 2);  // S pong

    size_t clr = (size_t)((char*)(pooled + NG * HD) - (char*)bucket_cnt);
    hipMemsetAsync(bucket_cnt, 0, clr, stream);

    hist_kernel<<<(NE + 2047) / 2048, 256, 0, stream>>>(ei, bucket_cnt);
    scan_kernel<<<1, 256, 0, stream>>>(bucket_cnt, bucket_base, bucket_cur);
    scatter_bin<<<(NE + 4095) / 4096, 256, 0, stream>>>(ei, bucket_cur, staging);
    place_kernel<<<NBUK, 256, 0, stream>>>(bucket_base, bucket_cnt, staging, row_beg,
                                           csrc, cedge);
    sege_kernel<<<(NN + 3) / 4, 256, 0, stream>>>(row_beg, cedge, ea, segaug);
    repack_kernel<<<dim3(8, 9), 256, 0, stream>>>(W1_msg, W1_self, W1_edge, b1_msg,
                                                  b1_edge, b1_self, Wk_msg, Wk_edge,
                                                  bk_msg, bk_edge, pack);

    // conv1: msg1 -> bufC, S1 = x@W1_self + edge-term -> bufS
    gemm_mfma_conv1<<<dim3((NN + 63) / 64), 256, 0, stream>>>(x, segaug, pack, bufC,
                                                              bufS, NN);
    // fused layers (h stays on-chip)
    fused_agg_gemm<<<NN / 16, 256, 0, stream>>>(row_beg, csrc, bufC, bufS, segaug,
                                                pack + 20480, pack + 69632, bufD, bufT);
    fused_agg_gemm<<<NN / 16, 256, 0, stream>>>(row_beg, csrc, bufD, bufT, segaug,
                                                pack + 20480 + 16384, pack + 69632 + 4096,
                                                bufC, bufS);
    fused_agg_gemm<<<NN / 16, 256, 0, stream>>>(row_beg, csrc, bufC, bufS, segaug,
                                                pack + 20480 + 32768, pack + 69632 + 8192,
                                                bufD, bufT);
    // final agg fused with mean-pool accumulation (h4 never hits global)
    agg_pool_kernel<<<NN / 16, 256, 0, stream>>>(row_beg, csrc, bufD, bufT, batch,
                                                 pooled);

    head_kernel<<<NG, HD, 0, stream>>>(pooled, batch, lf, pfe, Wl, bl, Wp, bp, Wf, bfv,
                                       Wo, bo, (float*)d_out);
}

// Round 6
// 347.980 us; speedup vs baseline: 1.5538x; 1.1767x over previous
//
#include <hip/hip_runtime.h>
#include <cstdint>

#define NN 50000
#define NE 640000
#define NG 128
#define HD 128
#define FN 64
#define FE 16
#define FL 200
#define FPOC 100
#define NSTACK 3
#define NBUK 196  // ceil(NN/256): dst-buckets of 256 nodes; bucket = d>>8

typedef unsigned short ushort_t;
typedef short short8 __attribute__((ext_vector_type(8)));
typedef float f32x4 __attribute__((ext_vector_type(4)));

__device__ __forceinline__ ushort_t f2bf(float f) {
    unsigned u = __float_as_uint(f);
    unsigned r = (u + 0x7fffu + ((u >> 16) & 1u)) >> 16;
    return (ushort_t)r;
}
__device__ __forceinline__ float bf2f(ushort_t u) {
    return __uint_as_float(((unsigned)u) << 16);
}

// ---------------- CSR build (round-12 bucketed scatter; proven) ----------------
// GATHER LEDGER (r0-r5): ILP-1 edge-balanced = -52% (r3); ILP-4 per-node
// quarter-wave = best (r0/r2); ILP-8@occ5+LDS = neutral (r1); ILP-8@occ6 =
// -15% (r5: FETCH 94MB, L2 thrash from 8-wide random bursts). ILP-4 IS THE
// OPTIMUM — do not change the gather width again.

__global__ void hist_kernel(const int* __restrict__ ei, int* __restrict__ bucket_cnt) {
    __shared__ int l[NBUK];
    int t = threadIdx.x;
    if (t < NBUK) l[t] = 0;
    __syncthreads();
    int base = blockIdx.x * 2048;
#pragma unroll
    for (int i = 0; i < 8; ++i) {
        int e = base + i * 256 + t;
        if (e < NE) atomicAdd(&l[ei[NE + e] >> 8], 1);
    }
    __syncthreads();
    if (t < NBUK && l[t]) atomicAdd(&bucket_cnt[t], l[t]);
}

__global__ void scan_kernel(const int* __restrict__ bucket_cnt,
                            int* __restrict__ bucket_base, int* __restrict__ bucket_cur) {
    __shared__ int s[256];
    int t = threadIdx.x;
    int v = (t < NBUK) ? bucket_cnt[t] : 0;
    s[t] = v;
    __syncthreads();
    for (int off = 1; off < 256; off <<= 1) {
        int w = (t >= off) ? s[t - off] : 0;
        __syncthreads();
        s[t] += w;
        __syncthreads();
    }
    if (t < NBUK) {
        int b = s[t] - v;
        bucket_base[t] = b;
        bucket_cur[t] = b;
    }
}

__global__ __launch_bounds__(256) void scatter_bin(const int* __restrict__ ei,
                                                   int* __restrict__ bucket_cur,
                                                   int2* __restrict__ staging) {
    __shared__ int lcnt[NBUK];
    __shared__ int lrun[NBUK];
    int t = threadIdx.x;
    if (t < NBUK) lcnt[t] = 0;
    __syncthreads();
    int base = blockIdx.x * 4096;
#pragma unroll
    for (int i = 0; i < 16; ++i) {
        int e = base + i * 256 + t;
        if (e < NE) atomicAdd(&lcnt[ei[NE + e] >> 8], 1);
    }
    __syncthreads();
    if (t < NBUK) {
        int c = lcnt[t];
        lrun[t] = c ? atomicAdd(&bucket_cur[t], c) : 0;
        lcnt[t] = 0;
    }
    __syncthreads();
#pragma unroll
    for (int i = 0; i < 16; ++i) {
        int e = base + i * 256 + t;
        if (e < NE) {
            int s = ei[e];
            int d = ei[NE + e];
            int bk = d >> 8;
            int off = atomicAdd(&lcnt[bk], 1);
            staging[lrun[bk] + off] = make_int2(s, e | ((d & 255) << 20));
        }
    }
}

// one block per bucket: LDS node-histogram + scan -> row_beg (global monotone,
// sentinel row_beg[NN]=NE), then LDS-cursor scatter into csrc/cedge.
__global__ __launch_bounds__(256) void place_kernel(
    const int* __restrict__ bucket_base, const int* __restrict__ bucket_cnt,
    const int2* __restrict__ staging, int* __restrict__ row_beg,
    int* __restrict__ csrc, int* __restrict__ cedge) {
    __shared__ int hist[256];
    __shared__ int curp[256];
    int t = threadIdx.x;
    int b = blockIdx.x;
    int n0 = b << 8;
    hist[t] = 0;
    __syncthreads();
    int ebase = bucket_base[b];
    int ecnt = bucket_cnt[b];
    for (int i = t; i < ecnt; i += 256) atomicAdd(&hist[staging[ebase + i].y >> 20], 1);
    __syncthreads();
    int v = hist[t];
    __syncthreads();
    for (int off = 1; off < 256; off <<= 1) {
        int w = (t >= off) ? hist[t - off] : 0;
        __syncthreads();
        hist[t] += w;
        __syncthreads();
    }
    int rb = ebase + hist[t] - v;  // exclusive prefix within bucket
    if (n0 + t < NN) row_beg[n0 + t] = rb;
    if (b == 0 && t == 0) row_beg[NN] = NE;
    curp[t] = rb;
    __syncthreads();
    for (int i = t; i < ecnt; i += 256) {
        int2 p = staging[ebase + i];
        int dl = p.y >> 20;
        int e = p.y & 0xFFFFF;
        int pos = atomicAdd(&curp[dl], 1);
        csrc[pos] = p.x;
        cedge[pos] = e;
    }
}

// segaug[v][32] (bf16) = [ segE[v][0..15], deg, 1, 0.. ]
__global__ __launch_bounds__(256) void sege_kernel(
    const int* __restrict__ row_beg, const int* __restrict__ cedge,
    const float* __restrict__ ea, ushort_t* __restrict__ segaug) {
    int node = blockIdx.x * 4 + (threadIdx.x >> 6);
    if (node >= NN) return;
    int lane = threadIdx.x & 63;
    int G = lane >> 2, q4 = (lane & 3) * 4;
    int beg = row_beg[node], end = row_beg[node + 1];
    int dg = end - beg;
    float4 a = make_float4(0.f, 0.f, 0.f, 0.f);
    for (int j = beg + G; j < end; j += 16) {
        int e = cedge[j];
        float4 v = *(const float4*)(ea + (size_t)e * FE + q4);
        a.x += v.x; a.y += v.y; a.z += v.z; a.w += v.w;
    }
    for (int m = 4; m <= 32; m <<= 1) {
        a.x += __shfl_xor(a.x, m);
        a.y += __shfl_xor(a.y, m);
        a.z += __shfl_xor(a.z, m);
        a.w += __shfl_xor(a.w, m);
    }
    if (lane < 4) {
        ushort_t o[4] = {f2bf(a.x), f2bf(a.y), f2bf(a.z), f2bf(a.w)};
        *(uint2*)(segaug + (size_t)node * 32 + lane * 4) = *(uint2*)o;
    } else if (lane < 8) {
        ushort_t o[4] = {0, 0, 0, 0};
        if (lane == 4) { o[0] = f2bf((float)dg); o[1] = f2bf(1.f); }
        *(uint2*)(segaug + (size_t)node * 32 + lane * 4) = *(uint2*)o;
    }
}

// ---------------- weight repack into MFMA B-fragment order ----------------
// 0:W1_msg K64 @0 | 1:W1_self K64 @8192 | 2:eaug1 K32 @16384
// 3..5: Wk_msg K128 @20480+i*16384 | 6..8: eaug_i K32 @69632+i*4096

__global__ void repack_kernel(const float* __restrict__ W1_msg,
                              const float* __restrict__ W1_self,
                              const float* __restrict__ W1_edge,
                              const float* __restrict__ b1_msg,
                              const float* __restrict__ b1_edge,
                              const float* __restrict__ b1_self,
                              const float* __restrict__ Wk_msg,
                              const float* __restrict__ Wk_edge,
                              const float* __restrict__ bk_msg,
                              const float* __restrict__ bk_edge,
                              ushort_t* __restrict__ pack) {
    int mid = blockIdx.y;
    const float *W = nullptr, *bm = nullptr, *be = nullptr, *bc = nullptr;
    int K;
    size_t doff;
    bool aug = false;
    if (mid == 0)      { W = W1_msg;  K = 64;  doff = 0; }
    else if (mid == 1) { W = W1_self; K = 64;  doff = 8192; }
    else if (mid == 2) { W = W1_edge; bm = b1_msg; be = b1_edge; bc = b1_self;
                         K = 32; doff = 16384; aug = true; }
    else if (mid <= 5) { int i = mid - 3; W = Wk_msg + (size_t)i * HD * HD;
                         K = 128; doff = 20480 + (size_t)i * 16384; }
    else               { int i = mid - 6; W = Wk_edge + (size_t)i * FE * HD;
                         bm = bk_msg + i * HD; be = bk_edge + i * HD;
                         K = 32; doff = 69632 + (size_t)i * 4096; aug = true; }
    int KS = K / 32;
    int t = blockIdx.x * 256 + threadIdx.x;
    if (t >= 8 * KS * 64) return;
    int lane = t & 63;
    int nk = t >> 6;
    int ks = nk % KS, nt = nk / KS;
    int n = nt * 16 + (lane & 15);
    int kb = ks * 32 + (lane >> 4) * 8;
    ushort_t o[8];
#pragma unroll
    for (int j = 0; j < 8; ++j) {
        int k = kb + j;
        float v;
        if (!aug)         v = W[(size_t)k * HD + n];
        else if (k < 16)  v = W[(size_t)k * HD + n];
        else if (k == 16) v = bm[n] + be[n];
        else if (k == 17) v = bc ? bc[n] : 0.f;
        else              v = 0.f;
        o[j] = f2bf(v);
    }
    *(uint4*)(pack + doff + (size_t)t * 8) = *(uint4*)o;
}

// ---------------- conv1 GEMM: Cm = x@W1_msg ; Cs = x@W1_self + segaug@eaug1 ----------------

__global__ __launch_bounds__(256) void gemm_mfma_conv1(const float* __restrict__ A,
                                                       const ushort_t* __restrict__ segaug,
                                                       const ushort_t* __restrict__ pack,
                                                       ushort_t* __restrict__ Cm,
                                                       ushort_t* __restrict__ Cs, int n) {
    constexpr int STR = 72, SSTR = 40;
    __shared__ __align__(16) ushort_t As[64 * STR];
    __shared__ __align__(16) ushort_t Ss[64 * SSTR];
    int tid = threadIdx.x;
    int row0 = blockIdx.x * 64;
#pragma unroll
    for (int p = 0; p < 2; ++p) {
        int c = p * 256 + tid;
        int r = c >> 3, col = (c & 7) * 8;
        int gr = row0 + r;
        float4 f0 = make_float4(0.f, 0.f, 0.f, 0.f), f1 = f0;
        if (gr < n) {
            f0 = *(const float4*)(A + (size_t)gr * FN + col);
            f1 = *(const float4*)(A + (size_t)gr * FN + col + 4);
        }
        ushort_t o[8] = {f2bf(f0.x), f2bf(f0.y), f2bf(f0.z), f2bf(f0.w),
                         f2bf(f1.x), f2bf(f1.y), f2bf(f1.z), f2bf(f1.w)};
        *(uint4*)(&As[r * STR + col]) = *(uint4*)o;
    }
    {
        int c = tid;
        int r = c >> 2, col = (c & 3) * 8;
        int gr = row0 + r;
        uint4 v = make_uint4(0u, 0u, 0u, 0u);
        if (gr < n) v = *(const uint4*)(segaug + (size_t)gr * 32 + col);
        *(uint4*)(&Ss[r * SSTR + col]) = v;
    }
    __syncthreads();
    int lane = tid & 63, wave = tid >> 6;
    int m = lane & 15, quad = lane >> 4;
    f32x4 acc[16];
#pragma unroll
    for (int i = 0; i < 16; ++i) acc[i] = (f32x4)(0.f);
    const short8* Bmsg = (const short8*)pack;
    const short8* Bself = (const short8*)(pack + 8192);
    const short8* Beaug = (const short8*)(pack + 16384);
#pragma unroll
    for (int ks = 0; ks < 2; ++ks) {
        short8 a = *(const short8*)(&As[(wave * 16 + m) * STR + ks * 32 + quad * 8]);
#pragma unroll
        for (int nt = 0; nt < 8; ++nt) {
            acc[nt] = __builtin_amdgcn_mfma_f32_16x16x32_bf16(
                a, Bmsg[(nt * 2 + ks) * 64 + lane], acc[nt], 0, 0, 0);
            acc[8 + nt] = __builtin_amdgcn_mfma_f32_16x16x32_bf16(
                a, Bself[(nt * 2 + ks) * 64 + lane], acc[8 + nt], 0, 0, 0);
        }
    }
    {
        short8 sa = *(const short8*)(&Ss[(wave * 16 + m) * SSTR + quad * 8]);
#pragma unroll
        for (int nt = 0; nt < 8; ++nt)
            acc[8 + nt] = __builtin_amdgcn_mfma_f32_16x16x32_bf16(
                sa, Beaug[nt * 64 + lane], acc[8 + nt], 0, 0, 0);
    }
#pragma unroll
    for (int nt = 0; nt < 8; ++nt) {
        int col = nt * 16 + m;
#pragma unroll
        for (int r = 0; r < 4; ++r) {
            int grow = row0 + wave * 16 + quad * 4 + r;
            if (grow < n) {
                Cm[(size_t)grow * HD + col] = f2bf(acc[nt][r]);
                Cs[(size_t)grow * HD + col] = f2bf(acc[8 + nt][r]);
            }
        }
    }
}

// ---------------- fused layer kernel: agg_i + gemm_{i+1} ----------------
// Round-16: EXACT round-2 unroll-4 gather body (the proven optimum), with
// csrc 4B index stream + row_beg sentinel retained.

__device__ __forceinline__ void accum8(float* a, uint4 v) {
    a[0] += __uint_as_float(v.x << 16);
    a[1] += __uint_as_float(v.x & 0xffff0000u);
    a[2] += __uint_as_float(v.y << 16);
    a[3] += __uint_as_float(v.y & 0xffff0000u);
    a[4] += __uint_as_float(v.z << 16);
    a[5] += __uint_as_float(v.z & 0xffff0000u);
    a[6] += __uint_as_float(v.w << 16);
    a[7] += __uint_as_float(v.w & 0xffff0000u);
}

#define AGG_LOOP(SRCBUF)                                                       \
    {                                                                          \
        int j = beg;                                                           \
        for (; j + 3 < end; j += 4) {                                          \
            int u0 = csrc[j], u1 = csrc[j + 1], u2 = csrc[j + 2],              \
                u3 = csrc[j + 3];                                              \
            uint4 v0 = *(const uint4*)(SRCBUF + (size_t)u0 * HD + c8);         \
            uint4 v1 = *(const uint4*)(SRCBUF + (size_t)u1 * HD + c8);         \
            uint4 v2 = *(const uint4*)(SRCBUF + (size_t)u2 * HD + c8);         \
            uint4 v3 = *(const uint4*)(SRCBUF + (size_t)u3 * HD + c8);         \
            accum8(a0, v0);                                                    \
            accum8(a1, v1);                                                    \
            accum8(a0, v2);                                                    \
            accum8(a1, v3);                                                    \
        }                                                                      \
        for (; j < end; ++j) {                                                 \
            uint4 v = *(const uint4*)(SRCBUF + (size_t)csrc[j] * HD + c8);     \
            accum8(a0, v);                                                     \
        }                                                                      \
    }

__global__ __launch_bounds__(256, 6) void fused_agg_gemm(
    const int* __restrict__ row_beg, const int* __restrict__ csrc,
    const ushort_t* __restrict__ msg_in, const ushort_t* __restrict__ S_in,
    const ushort_t* __restrict__ segaug, const ushort_t* __restrict__ Bm,
    const ushort_t* __restrict__ Be, ushort_t* __restrict__ msg_out,
    ushort_t* __restrict__ S_out) {
    constexpr int STR = 136, SSTR = 40;
    __shared__ __align__(16) ushort_t Hs[16 * STR];
    __shared__ __align__(16) ushort_t Ss[16 * SSTR];
    int tid = threadIdx.x;
    int node0 = blockIdx.x * 16;
    if (tid < 64) {
        int r = tid >> 2, col = (tid & 3) * 8;
        *(uint4*)(&Ss[r * SSTR + col]) =
            *(const uint4*)(segaug + (size_t)(node0 + r) * 32 + col);
    }
    int nl = tid >> 4;
    int node = node0 + nl;
    int c8 = (tid & 15) * 8;
    int beg = row_beg[node];
    int end = row_beg[node + 1];
    float a0[8] = {0.f, 0.f, 0.f, 0.f, 0.f, 0.f, 0.f, 0.f};
    float a1[8] = {0.f, 0.f, 0.f, 0.f, 0.f, 0.f, 0.f, 0.f};
    AGG_LOOP(msg_in)
    accum8(a0, *(const uint4*)(S_in + (size_t)node * HD + c8));
    {
        ushort_t h8[8];
#pragma unroll
        for (int i = 0; i < 8; ++i) h8[i] = f2bf(fmaxf(a0[i] + a1[i], 0.f));
        *(uint4*)(&Hs[nl * STR + c8]) = *(uint4*)h8;
    }
    __syncthreads();
    int lane = tid & 63, wave = tid >> 6;
    int m = lane & 15, quad = lane >> 4;
    f32x4 acc[2], accE[2];
#pragma unroll
    for (int t = 0; t < 2; ++t) { acc[t] = (f32x4)(0.f); accE[t] = (f32x4)(0.f); }
    const short8* Bmv = (const short8*)Bm;
    const short8* Bev = (const short8*)Be;
#pragma unroll
    for (int ks = 0; ks < 4; ++ks) {
        short8 a = *(const short8*)(&Hs[m * STR + ks * 32 + quad * 8]);
#pragma unroll
        for (int t = 0; t < 2; ++t) {
            int nt = wave * 2 + t;
            acc[t] = __builtin_amdgcn_mfma_f32_16x16x32_bf16(
                a, Bmv[(nt * 4 + ks) * 64 + lane], acc[t], 0, 0, 0);
        }
    }
    {
        short8 sa = *(const short8*)(&Ss[m * SSTR + quad * 8]);
#pragma unroll
        for (int t = 0; t < 2; ++t) {
            int nt = wave * 2 + t;
            accE[t] = __builtin_amdgcn_mfma_f32_16x16x32_bf16(
                sa, Bev[nt * 64 + lane], accE[t], 0, 0, 0);
        }
    }
#pragma unroll
    for (int t = 0; t < 2; ++t) {
        int col = (wave * 2 + t) * 16 + m;
#pragma unroll
        for (int r = 0; r < 4; ++r) {
            int rl = quad * 4 + r;
            size_t gidx = (size_t)(node0 + rl) * HD + col;
            msg_out[gidx] = f2bf(acc[t][r]);
            S_out[gidx] = f2bf(accE[t][r] + bf2f(Hs[rl * STR + col]));
        }
    }
}

// ---------------- final aggregate fused with pooling ----------------
// h4 = relu(gather + S) is consumed ONLY by mean-pool -> never write it to
// global. Round-2 gather shape + csrc index stream.

__global__ __launch_bounds__(256, 6) void agg_pool_kernel(
    const int* __restrict__ row_beg, const int* __restrict__ csrc,
    const ushort_t* __restrict__ xm, const ushort_t* __restrict__ selfb,
    const int* __restrict__ batch, float* __restrict__ pooled) {
    __shared__ float hloc[16][HD];
    int tid = threadIdx.x;
    int node0 = blockIdx.x * 16;
    int nl = tid >> 4;
    int node = node0 + nl;
    int c8 = (tid & 15) * 8;
    int beg = row_beg[node];
    int end = row_beg[node + 1];
    float a0[8] = {0.f, 0.f, 0.f, 0.f, 0.f, 0.f, 0.f, 0.f};
    float a1[8] = {0.f, 0.f, 0.f, 0.f, 0.f, 0.f, 0.f, 0.f};
    AGG_LOOP(xm)
    accum8(a0, *(const uint4*)(selfb + (size_t)node * HD + c8));
#pragma unroll
    for (int i = 0; i < 8; ++i) hloc[nl][c8 + i] = fmaxf(a0[i] + a1[i], 0.f);
    __syncthreads();
    if (tid < HD) {
        int f = tid;
        float run = 0.f;
        int gprev = batch[node0];
        for (int r = 0; r < 16; ++r) {
            int g = batch[node0 + r];
            if (g != gprev) {
                atomicAdd(&pooled[gprev * HD + f], run);
                run = 0.f;
                gprev = g;
            }
            run += hloc[r][f];
        }
        atomicAdd(&pooled[gprev * HD + f], run);
    }
}

// ---------------- fusion head (reads completed pooled sums) ----------------

__global__ void head_kernel(const float* __restrict__ pooled, const int* __restrict__ batch,
                            const float* __restrict__ lf, const float* __restrict__ pfe,
                            const float* __restrict__ Wl, const float* __restrict__ bl,
                            const float* __restrict__ Wp, const float* __restrict__ bp,
                            const float* __restrict__ Wf, const float* __restrict__ bfv,
                            const float* __restrict__ Wo, const float* __restrict__ bo,
                            float* __restrict__ out) {
    __shared__ float cat[3 * HD];
    __shared__ float red[HD];
    int g = blockIdx.x, j = threadIdx.x;
    int lo = 0, hi = NN;
    while (lo < hi) { int m = (lo + hi) >> 1; if (batch[m] < g) lo = m + 1; else hi = m; }
    int s0 = lo;
    lo = s0; hi = NN;
    while (lo < hi) { int m = (lo + hi) >> 1; if (batch[m] < g + 1) lo = m + 1; else hi = m; }
    float cntf = (float)(lo - s0);
    cat[j] = pooled[(size_t)g * HD + j] / fmaxf(cntf, 1.f);
    float s = bl[j];
    for (int k = 0; k < FL; ++k) s += lf[g * FL + k] * Wl[k * HD + j];
    cat[HD + j] = s;
    s = bp[j];
    for (int k = 0; k < FPOC; ++k) s += pfe[g * FPOC + k] * Wp[k * HD + j];
    cat[2 * HD + j] = s;
    __syncthreads();
    float fj = bfv[j];
    for (int k = 0; k < 3 * HD; ++k) fj += cat[k] * Wf[k * HD + j];
    red[j] = fj * Wo[j];
    __syncthreads();
    for (int off = 64; off > 0; off >>= 1) {
        if (j < off) red[j] += red[j + off];
        __syncthreads();
    }
    if (j == 0) out[g] = red[0] + bo[0];
}

// ---------------- launch ----------------

extern "C" void kernel_launch(void* const* d_in, const int* in_sizes, int n_in,
                              void* d_out, int out_size, void* d_ws, size_t ws_size,
                              hipStream_t stream) {
    const float* x       = (const float*)d_in[0];
    const int*   ei      = (const int*)d_in[1];
    const float* ea      = (const float*)d_in[2];
    const int*   batch   = (const int*)d_in[3];
    const float* lf      = (const float*)d_in[4];
    const float* pfe     = (const float*)d_in[5];
    const float* W1_msg  = (const float*)d_in[6];
    const float* b1_msg  = (const float*)d_in[7];
    const float* W1_edge = (const float*)d_in[8];
    const float* b1_edge = (const float*)d_in[9];
    const float* W1_self = (const float*)d_in[10];
    const float* b1_self = (const float*)d_in[11];
    const float* Wk_msg  = (const float*)d_in[12];
    const float* bk_msg  = (const float*)d_in[13];
    const float* Wk_edge = (const float*)d_in[14];
    const float* bk_edge = (const float*)d_in[15];
    const float* Wl      = (const float*)d_in[16];
    const float* bl      = (const float*)d_in[17];
    const float* Wp      = (const float*)d_in[18];
    const float* bp      = (const float*)d_in[19];
    const float* Wf      = (const float*)d_in[20];
    const float* bfv     = (const float*)d_in[21];
    const float* Wo      = (const float*)d_in[22];
    const float* bo      = (const float*)d_in[23];

    char* wsp = (char*)d_ws;
    size_t off = 0;
    auto carve = [&](size_t bytes) -> void* {
        char* p = wsp + off;
        off += (bytes + 255) & ~(size_t)255;
        return (void*)p;
    };
    // zeroed span: bucket_cnt .. pooled (contiguous carves)
    int*      bucket_cnt  = (int*)carve((size_t)NBUK * 4);
    float*    pooled      = (float*)carve((size_t)NG * HD * 4);
    int*      bucket_base = (int*)carve((size_t)NBUK * 4);
    int*      bucket_cur  = (int*)carve((size_t)NBUK * 4);
    int*      row_beg     = (int*)carve((size_t)(NN + 1) * 4);
    int2*     staging     = (int2*)carve((size_t)NE * 8);
    int*      csrc        = (int*)carve((size_t)NE * 4);
    int*      cedge       = (int*)carve((size_t)NE * 4);
    ushort_t* segaug      = (ushort_t*)carve((size_t)NN * 32 * 2);
    ushort_t* pack        = (ushort_t*)carve((size_t)81920 * 2);
    ushort_t* bufC        = (ushort_t*)carve((size_t)NN * HD * 2);  // msg ping
    ushort_t* bufD        = (ushort_t*)carve((size_t)NN * HD * 2);  // msg pong
    ushort_t* bufS        = (ushort_t*)carve((size_t)NN * HD * 2);  // S ping
    ushort_t* bufT        = (ushort_t*)carve((size_t)NN * HD * 2);  // S pong

    size_t clr = (size_t)((char*)(pooled + NG * HD) - (char*)bucket_cnt);
    hipMemsetAsync(bucket_cnt, 0, clr, stream);

    hist_kernel<<<(NE + 2047) / 2048, 256, 0, stream>>>(ei, bucket_cnt);
    scan_kernel<<<1, 256, 0, stream>>>(bucket_cnt, bucket_base, bucket_cur);
    scatter_bin<<<(NE + 4095) / 4096, 256, 0, stream>>>(ei, bucket_cur, staging);
    place_kernel<<<NBUK, 256, 0, stream>>>(bucket_base, bucket_cnt, staging, row_beg,
                                           csrc, cedge);
    sege_kernel<<<(NN + 3) / 4, 256, 0, stream>>>(row_beg, cedge, ea, segaug);
    repack_kernel<<<dim3(8, 9), 256, 0, stream>>>(W1_msg, W1_self, W1_edge, b1_msg,
                                                  b1_edge, b1_self, Wk_msg, Wk_edge,
                                                  bk_msg, bk_edge, pack);

    // conv1: msg1 -> bufC, S1 = x@W1_self + edge-term -> bufS
    gemm_mfma_conv1<<<dim3((NN + 63) / 64), 256, 0, stream>>>(x, segaug, pack, bufC,
                                                              bufS, NN);
    // fused layers (h stays on-chip)
    fused_agg_gemm<<<NN / 16, 256, 0, stream>>>(row_beg, csrc, bufC, bufS, segaug,
                                                pack + 20480, pack + 69632, bufD, bufT);
    fused_agg_gemm<<<NN / 16, 256, 0, stream>>>(row_beg, csrc, bufD, bufT, segaug,
                                                pack + 20480 + 16384, pack + 69632 + 4096,
                                                bufC, bufS);
    fused_agg_gemm<<<NN / 16, 256, 0, stream>>>(row_beg, csrc, bufC, bufS, segaug,
                                                pack + 20480 + 32768, pack + 69632 + 8192,
                                                bufD, bufT);
    // final agg fused with mean-pool accumulation (h4 never hits global)
    agg_pool_kernel<<<NN / 16, 256, 0, stream>>>(row_beg, csrc, bufD, bufT, batch,
                                                 pooled);

    head_kernel<<<NG, HD, 0, stream>>>(pooled, batch, lf, pfe, Wl, bl, Wp, bp, Wf, bfv,
                                       Wo, bo, (float*)d_out);
}